// Round 9
// baseline (404.240 us; speedup 1.0000x reference)
//
#include <hip/hip_runtime.h>

#define NF 64        // IN_F == HID_F == 64
#define BKSH 9       // bucket = dst >> 9 (512 nodes/bucket)
#define BKN 512      // nodes per bucket
#define SB 256       // superblocks (edge partitions)

typedef unsigned short u16;
typedef __attribute__((ext_vector_type(8))) short bf16x8;
typedef __attribute__((ext_vector_type(4))) float f32x4;

__device__ __forceinline__ float bf2f(unsigned h) {
    return __uint_as_float(h << 16);
}
__device__ __forceinline__ u16 f2bf(float x) {   // round-to-nearest-even
    unsigned u = __float_as_uint(x);
    return (u16)((u + 0x7FFFu + ((u >> 16) & 1u)) >> 16);
}

// ============ CSR build: two-phase radix partition ============
// LESSONS ledger: no __threadfence last-block fusion (r6: +32us); no
// grid-shrinking fusion of streaming work (r5: +35us); no barrier-coupled
// fusion of gather phases with compute (r7: +18us). bucket_scan kernel is
// eliminated fence-free: hist_scan/radix_build recompute the 196-entry
// bucket prefix in-block (~1us redundant LDS scan, no serialization).

__launch_bounds__(256)
__global__ void radix_count(const int* __restrict__ dst, int* __restrict__ hist,
                            int* __restrict__ bucket_total, int E, int epb, int nbuk) {
    __shared__ int bins[BKN];
    int tid = threadIdx.x, sb = blockIdx.x;
    for (int i = tid; i < nbuk; i += 256) bins[i] = 0;
    __syncthreads();
    int base = sb * epb;
    int end = min(base + epb, E);
    for (int e = base + tid; e < end; e += 256)
        atomicAdd(&bins[dst[e] >> BKSH], 1);
    __syncthreads();
    for (int i = tid; i < nbuk; i += 256) {
        int c = bins[i];
        hist[i * SB + sb] = c;
        if (c) atomicAdd(&bucket_total[i], c);
    }
}

__global__ void hist_scan(int* __restrict__ hist, const int* __restrict__ bucket_total,
                          int nbuk) {
    __shared__ int s[256];
    int b = blockIdx.x, tid = threadIdx.x;
    // pass 1: in-block exclusive bucket base (replaces bucket_scan kernel)
    int bv = (tid < nbuk) ? bucket_total[tid] : 0;
    s[tid] = bv; __syncthreads();
    for (int off = 1; off < 256; off <<= 1) {
        int t = (tid >= off) ? s[tid - off] : 0;
        __syncthreads();
        s[tid] += t;
        __syncthreads();
    }
    int bbase = s[b] - bucket_total[b];
    __syncthreads();
    // pass 2: scan this bucket's per-superblock counts
    int v = hist[b * SB + tid];
    s[tid] = v; __syncthreads();
    for (int off = 1; off < 256; off <<= 1) {
        int t = (tid >= off) ? s[tid - off] : 0;
        __syncthreads();
        s[tid] += t;
        __syncthreads();
    }
    hist[b * SB + tid] = bbase + s[tid] - v;
}

__launch_bounds__(256)
__global__ void radix_scatter(const int* __restrict__ src, const int* __restrict__ dst,
                              const int* __restrict__ hist, int* __restrict__ tmp,
                              int E, int epb, int nbuk) {
    __shared__ int cur[BKN];
    int tid = threadIdx.x, sb = blockIdx.x;
    for (int i = tid; i < nbuk; i += 256) cur[i] = hist[i * SB + sb];
    __syncthreads();
    int base = sb * epb;
    int end = min(base + epb, E);
    for (int e = base + tid; e < end; e += 256) {
        int d = dst[e];
        int b = d >> BKSH;
        int pos = atomicAdd(&cur[b], 1);
        tmp[pos] = ((d & (BKN - 1)) << 17) | src[e];
    }
}

__launch_bounds__(256)
__global__ void radix_build(const int* __restrict__ tmp, const int* __restrict__ bucket_total,
                            int* __restrict__ csr_src, int* __restrict__ rowptr,
                            float* __restrict__ dinv, int N, int nbuk) {
    __shared__ int cnt[BKN], excl[BKN], cur[BKN];
    __shared__ int s[256];
    int b = blockIdx.x, tid = threadIdx.x;
    // in-block bucket prefix (replaces bucket_base array)
    int bv = (tid < nbuk) ? bucket_total[tid] : 0;
    s[tid] = bv; __syncthreads();
    for (int off = 1; off < 256; off <<= 1) {
        int t = (tid >= off) ? s[tid - off] : 0;
        __syncthreads();
        s[tid] += t;
        __syncthreads();
    }
    int end = s[b];
    int beg = end - bucket_total[b];
    __syncthreads();
    cnt[tid] = 0; cnt[tid + 256] = 0;
    __syncthreads();
    for (int e = beg + tid; e < end; e += 256)
        atomicAdd(&cnt[(tmp[e] >> 17) & (BKN - 1)], 1);
    __syncthreads();
    int c0 = cnt[2 * tid], c1 = cnt[2 * tid + 1];
    int v = c0 + c1;
    s[tid] = v; __syncthreads();
    for (int off = 1; off < 256; off <<= 1) {
        int t = (tid >= off) ? s[tid - off] : 0;
        __syncthreads();
        s[tid] += t;
        __syncthreads();
    }
    int base2 = s[tid] - v;
    excl[2 * tid] = base2;
    excl[2 * tid + 1] = base2 + c0;
    cur[2 * tid] = 0; cur[2 * tid + 1] = 0;
    int node0 = b << BKSH;
    int n0 = node0 + 2 * tid, n1 = n0 + 1;
    if (n0 < N) { rowptr[n0] = beg + base2;      dinv[n0] = rsqrtf(fmaxf((float)c0, 1.0f)); }
    if (n1 < N) { rowptr[n1] = beg + base2 + c0; dinv[n1] = rsqrtf(fmaxf((float)c1, 1.0f)); }
    __syncthreads();
    for (int e = beg + tid; e < end; e += 256) {
        int vv = tmp[e];
        int dlow = (vv >> 17) & (BKN - 1);
        int pos = excl[dlow] + atomicAdd(&cur[dlow], 1);
        csr_src[beg + pos] = vv & 0x1FFFF;
    }
}

// ============ prescale (+ weight transpose tail + rowptr sentinel) ============
// Ya = bf16(X*dinv), Fb = bf16(X); threads i < 192*96 also convert one W element.
__global__ void prescale(const float* __restrict__ X, const float* __restrict__ dinv,
                         u16* __restrict__ Ya, u16* __restrict__ Fb,
                         const float* __restrict__ W1, const float* __restrict__ W2,
                         u16* __restrict__ Wt1, u16* __restrict__ Wt2,
                         int* __restrict__ rowptr, int N, int E, int total4) {
    int i = blockIdx.x * blockDim.x + threadIdx.x;
    if (i == 0) rowptr[N] = E;   // sentinel (consumed first by spmm_m1, launched later)
    if (i < total4) {
        int node = i >> 4;
        float dn = dinv[node];
        float4 v = ((const float4*)X)[i];
        ushort4 ys, yu;
        ys.x = f2bf(v.x * dn); ys.y = f2bf(v.y * dn);
        ys.z = f2bf(v.z * dn); ys.w = f2bf(v.w * dn);
        yu.x = f2bf(v.x); yu.y = f2bf(v.y); yu.z = f2bf(v.z); yu.w = f2bf(v.w);
        ((ushort4*)Ya)[i] = ys;
        ((ushort4*)Fb)[i] = yu;
    }
    if (i < 192 * 64) {
        int k = i >> 6, c = i & 63;
        Wt1[(size_t)c * 192 + k] = f2bf(W1[i]);
    } else if (i < 192 * 64 + 192 * 32) {
        int j = i - 192 * 64;
        int k = j >> 5, c = j & 31;
        Wt2[(size_t)c * 192 + k] = f2bf(W2[j]);
    }
}

// ============ gather core: 8 lanes/node, x8 unroll, uint4 index loads ============
// Round-3 proven form. FETCH is at the XCD-replication compulsory floor
// (~85 MB/pass); fill path ~2.5 TB/s is the HW rate for random 128B granules.

#define ACC8(A, u) \
    A[0] += bf2f(u.x & 0xFFFFu); A[1] += bf2f(u.x >> 16); \
    A[2] += bf2f(u.y & 0xFFFFu); A[3] += bf2f(u.y >> 16); \
    A[4] += bf2f(u.z & 0xFFFFu); A[5] += bf2f(u.z >> 16); \
    A[6] += bf2f(u.w & 0xFFFFu); A[7] += bf2f(u.w >> 16);

__device__ __forceinline__ void gather8(const u16* __restrict__ Yf,
                                        const int* __restrict__ csr_src,
                                        int beg, int end, float* __restrict__ out) {
    float acc[8], acc2[8];
#pragma unroll
    for (int j = 0; j < 8; ++j) { acc[j] = 0.f; acc2[j] = 0.f; }
    int e = beg;
    int pre = min(end, (beg + 3) & ~3);            // align e to 4 for uint4 idx loads
    for (; e < pre; ++e) {
        int s = csr_src[e];
        uint4 u = *(const uint4*)(Yf + (size_t)s * NF);
        ACC8(acc, u);
    }
    for (; e + 8 <= end; e += 8) {
        uint4 sA = *(const uint4*)(csr_src + e);
        uint4 sB = *(const uint4*)(csr_src + e + 4);
        uint4 u0 = *(const uint4*)(Yf + (size_t)sA.x * NF);
        uint4 u1 = *(const uint4*)(Yf + (size_t)sA.y * NF);
        uint4 u2 = *(const uint4*)(Yf + (size_t)sA.z * NF);
        uint4 u3 = *(const uint4*)(Yf + (size_t)sA.w * NF);
        uint4 u4 = *(const uint4*)(Yf + (size_t)sB.x * NF);
        uint4 u5 = *(const uint4*)(Yf + (size_t)sB.y * NF);
        uint4 u6 = *(const uint4*)(Yf + (size_t)sB.z * NF);
        uint4 u7 = *(const uint4*)(Yf + (size_t)sB.w * NF);
        ACC8(acc, u0); ACC8(acc2, u1); ACC8(acc, u2); ACC8(acc2, u3);
        ACC8(acc, u4); ACC8(acc2, u5); ACC8(acc, u6); ACC8(acc2, u7);
    }
    if (e + 4 <= end) {
        uint4 sA = *(const uint4*)(csr_src + e);
        uint4 u0 = *(const uint4*)(Yf + (size_t)sA.x * NF);
        uint4 u1 = *(const uint4*)(Yf + (size_t)sA.y * NF);
        uint4 u2 = *(const uint4*)(Yf + (size_t)sA.z * NF);
        uint4 u3 = *(const uint4*)(Yf + (size_t)sA.w * NF);
        ACC8(acc, u0); ACC8(acc2, u1); ACC8(acc, u2); ACC8(acc2, u3);
        e += 4;
    }
    if (e + 2 <= end) {
        int2 sA = *(const int2*)(csr_src + e);
        uint4 u0 = *(const uint4*)(Yf + (size_t)sA.x * NF);
        uint4 u1 = *(const uint4*)(Yf + (size_t)sA.y * NF);
        ACC8(acc, u0); ACC8(acc2, u1);
        e += 2;
    }
    if (e < end) {
        int s = csr_src[e];
        uint4 u = *(const uint4*)(Yf + (size_t)s * NF);
        ACC8(acc, u);
    }
#pragma unroll
    for (int j = 0; j < 8; ++j) out[j] = acc[j] + acc2[j];
}

// mode 1: X1b = bf16(-acc*dinv)  (gemm operand),  Yout = bf16(-acc*dinv^2)  (next gather)
__launch_bounds__(256)
__global__ void spmm_m1(const u16* __restrict__ Y, const int* __restrict__ rowptr,
                        const int* __restrict__ csr_src, const float* __restrict__ dinv,
                        u16* __restrict__ Yout, u16* __restrict__ X1b, int n) {
    int node = (int)((blockIdx.x * blockDim.x + threadIdx.x) >> 3);
    if (node >= n) return;
    int fl = (threadIdx.x & 7) << 3;
    float acc[8];
    gather8(Y + fl, csr_src, rowptr[node], rowptr[node + 1], acc);
    float dn = dinv[node];
    float r[8];
#pragma unroll
    for (int j = 0; j < 8; ++j) r[j] = -acc[j] * dn;
    uint4 ub, uy;
    ub.x = (unsigned)f2bf(r[0]) | ((unsigned)f2bf(r[1]) << 16);
    ub.y = (unsigned)f2bf(r[2]) | ((unsigned)f2bf(r[3]) << 16);
    ub.z = (unsigned)f2bf(r[4]) | ((unsigned)f2bf(r[5]) << 16);
    ub.w = (unsigned)f2bf(r[6]) | ((unsigned)f2bf(r[7]) << 16);
    uy.x = (unsigned)f2bf(r[0] * dn) | ((unsigned)f2bf(r[1] * dn) << 16);
    uy.y = (unsigned)f2bf(r[2] * dn) | ((unsigned)f2bf(r[3] * dn) << 16);
    uy.z = (unsigned)f2bf(r[4] * dn) | ((unsigned)f2bf(r[5] * dn) << 16);
    uy.w = (unsigned)f2bf(r[6] * dn) | ((unsigned)f2bf(r[7] * dn) << 16);
    *(uint4*)(X1b + (size_t)node * NF + fl) = ub;
    *(uint4*)(Yout + (size_t)node * NF + fl) = uy;
}

// mode 2: X2b = bf16(-2*acc*dinv - Xprev),  Xprev is bf16
__launch_bounds__(256)
__global__ void spmm_m2(const u16* __restrict__ Y, const int* __restrict__ rowptr,
                        const int* __restrict__ csr_src, const float* __restrict__ dinv,
                        const u16* __restrict__ Xprev, u16* __restrict__ X2b, int n) {
    int node = (int)((blockIdx.x * blockDim.x + threadIdx.x) >> 3);
    if (node >= n) return;
    int fl = (threadIdx.x & 7) << 3;
    float acc[8];
    gather8(Y + fl, csr_src, rowptr[node], rowptr[node + 1], acc);
    float dn = dinv[node];
    uint4 up = *(const uint4*)(Xprev + (size_t)node * NF + fl);
    float xp[8];
    xp[0] = bf2f(up.x & 0xFFFFu); xp[1] = bf2f(up.x >> 16);
    xp[2] = bf2f(up.y & 0xFFFFu); xp[3] = bf2f(up.y >> 16);
    xp[4] = bf2f(up.z & 0xFFFFu); xp[5] = bf2f(up.z >> 16);
    xp[6] = bf2f(up.w & 0xFFFFu); xp[7] = bf2f(up.w >> 16);
    float r[8];
#pragma unroll
    for (int j = 0; j < 8; ++j) r[j] = -2.f * acc[j] * dn - xp[j];
    uint4 uy;
    uy.x = (unsigned)f2bf(r[0]) | ((unsigned)f2bf(r[1]) << 16);
    uy.y = (unsigned)f2bf(r[2]) | ((unsigned)f2bf(r[3]) << 16);
    uy.z = (unsigned)f2bf(r[4]) | ((unsigned)f2bf(r[5]) << 16);
    uy.w = (unsigned)f2bf(r[6]) | ((unsigned)f2bf(r[7]) << 16);
    *(uint4*)(X2b + (size_t)node * NF + fl) = uy;
}

// ============ GEMM v6 (MFMA): C[N x OUTF] = [X0b|X1b|X2b] @ W + b ============
// Wave = 16 nodes; block = 4 waves = 64 nodes. A[m=lane&15][k=q*8+j] (m120-verified),
// B symmetric via Wt[c][k] (contiguous k), D: col=lane&15, row=q*4+reg (m89-verified).
// No LDS. Layer1 (OUTF=64): writes Hb=bf16(H), Ya=bf16(H*dinv). Layer2: fp32 out.
template <int OUTF>
__launch_bounds__(256)
__global__ void gemm_mfma(const u16* __restrict__ X0b, const u16* __restrict__ X1b,
                          const u16* __restrict__ X2b, const u16* __restrict__ Wt,
                          const float* __restrict__ bias, const float* __restrict__ dinv,
                          float* __restrict__ outp, u16* __restrict__ Ya,
                          u16* __restrict__ Hb, int n, int do_relu) {
    constexpr int NT = OUTF / 16;   // 4 or 2 N-tiles
    const int wave = threadIdx.x >> 6;
    const int lane = threadIdx.x & 63;
    const int node0 = blockIdx.x * 64 + wave * 16;
    const int m = lane & 15;
    const int q = lane >> 4;
    const int arow = min(node0 + m, n - 1);   // OOB rows only corrupt unstored D rows

    union U8 { uint4 u; bf16x8 v; };

    f32x4 acc[NT];
#pragma unroll
    for (int t = 0; t < NT; ++t) acc[t] = (f32x4){0.f, 0.f, 0.f, 0.f};

    const u16* Xs[3] = {X0b, X1b, X2b};
#pragma unroll
    for (int p = 0; p < 3; ++p) {
        const u16* __restrict__ Xc = Xs[p];
#pragma unroll
        for (int h = 0; h < 2; ++h) {
            U8 a;
            a.u = *(const uint4*)(Xc + (size_t)arow * 64 + h * 32 + q * 8);
#pragma unroll
            for (int t = 0; t < NT; ++t) {
                U8 b;
                b.u = *(const uint4*)(Wt + (size_t)(t * 16 + m) * 192 + p * 64 + h * 32 + q * 8);
                acc[t] = __builtin_amdgcn_mfma_f32_16x16x32_bf16(a.v, b.v, acc[t], 0, 0, 0);
            }
        }
    }

    // epilogue: lane holds D[row=node0+q*4+r][col=t*16+m]
    float dv[4];
#pragma unroll
    for (int r = 0; r < 4; ++r) {
        int row = node0 + q * 4 + r;
        dv[r] = (OUTF == 64 && row < n) ? dinv[row] : 0.f;
    }
#pragma unroll
    for (int t = 0; t < NT; ++t) {
        int col = t * 16 + m;
        float bv = bias[col];
#pragma unroll
        for (int r = 0; r < 4; ++r) {
            int row = node0 + q * 4 + r;
            if (row < n) {
                float v = acc[t][r] + bv;
                if (do_relu) v = fmaxf(v, 0.f);
                if (OUTF == 64) {
                    Hb[(size_t)row * 64 + col] = f2bf(v);
                    Ya[(size_t)row * 64 + col] = f2bf(v * dv[r]);
                } else {
                    outp[(size_t)row * 32 + col] = v;
                }
            }
        }
    }
}

extern "C" void kernel_launch(void* const* d_in, const int* in_sizes, int n_in,
                              void* d_out, int out_size, void* d_ws, size_t ws_size,
                              hipStream_t stream) {
    const float* feat = (const float*)d_in[0];
    const int*   src  = (const int*)d_in[1];
    const int*   dst  = (const int*)d_in[2];
    const float* W1   = (const float*)d_in[3];
    const float* b1   = (const float*)d_in[4];
    const float* W2   = (const float*)d_in[5];
    const float* b2   = (const float*)d_in[6];
    float* out = (float*)d_out;

    const int N = in_sizes[0] / NF;   // 100000
    const int E = in_sizes[1];        // 1600000
    const size_t NFtot = (size_t)N * NF;
    const int nbuk = (N + BKN - 1) >> BKSH;   // 196
    const int epb = (E + SB - 1) / SB;        // 6250

    // workspace layout (16B-aligned chunks)
    char* p = (char*)d_ws;
    int* hist         = (int*)p;   p += (size_t)BKN * SB * 4;
    int* bucket_total = (int*)p;   p += (BKN + 16) * 4;
    int* rowptr       = (int*)p;   p += ((size_t)N + 16) * 4;
    int* csr_src      = (int*)p;   p += (size_t)E * 4;
    float* dinv       = (float*)p; p += ((size_t)N + 16) * 4;
    u16* Wt1          = (u16*)p;   p += 192 * 64 * 2;
    u16* Wt2          = (u16*)p;   p += 192 * 32 * 2;
    u16* Ya           = (u16*)p;   p += NFtot * 2;   // bf16(X0*dinv) gather table
    u16* Yb           = (u16*)p;   p += NFtot * 2;   // bf16(X1*dinv^2) gather table
    u16* X1b          = (u16*)p;   p += NFtot * 2;   // bf16(X1) gemm operand
    u16* X2b          = (u16*)p;   p += NFtot * 2;   // bf16(X2) gemm operand
    u16* Fb           = (u16*)p;   p += NFtot * 2;   // bf16(feat)
    u16* Hb           = (u16*)p;   p += NFtot * 2;   // bf16(H)
    int* tmp = (int*)Yb;           // alias Yb; consumed by radix_build before spmm_m1 writes Yb

    const int TB = 256;
    dim3 blk(TB);
    dim3 gW8(((size_t)N * 8 + TB - 1) / TB);    // 8 lanes per node
    dim3 gPre(((size_t)N * 16 + TB - 1) / TB);
    dim3 gGemm((N + 63) / 64);

    // ---- CSR build (radix partition; 4 kernels, no fences, no 1-block scan) ----
    hipMemsetAsync(bucket_total, 0, (size_t)(BKN + 1) * sizeof(int), stream);
    radix_count<<<dim3(SB), blk, 0, stream>>>(dst, hist, bucket_total, E, epb, nbuk);
    hist_scan<<<dim3(nbuk), blk, 0, stream>>>(hist, bucket_total, nbuk);
    radix_scatter<<<dim3(SB), blk, 0, stream>>>(src, dst, hist, tmp, E, epb, nbuk);
    radix_build<<<dim3(nbuk), blk, 0, stream>>>(tmp, bucket_total, csr_src, rowptr, dinv, N, nbuk);

    // ---- prescale + weight transpose + rowptr sentinel (one full-grid launch) ----
    prescale<<<gPre, blk, 0, stream>>>(feat, dinv, Ya, Fb, W1, W2, Wt1, Wt2,
                                       rowptr, N, E, (int)(N * 16));

    // ---- layer 1 ----
    spmm_m1<<<gW8, blk, 0, stream>>>(Ya, rowptr, csr_src, dinv, Yb, X1b, N);
    spmm_m2<<<gW8, blk, 0, stream>>>(Yb, rowptr, csr_src, dinv, Fb, X2b, N);
    gemm_mfma<64><<<gGemm, blk, 0, stream>>>(Fb, X1b, X2b, Wt1, b1, dinv,
                                             nullptr, Ya, Hb, N, 1);

    // ---- layer 2 ----
    spmm_m1<<<gW8, blk, 0, stream>>>(Ya, rowptr, csr_src, dinv, Yb, X1b, N);
    spmm_m2<<<gW8, blk, 0, stream>>>(Yb, rowptr, csr_src, dinv, Hb, X2b, N);
    gemm_mfma<32><<<gGemm, blk, 0, stream>>>(Hb, X1b, X2b, Wt2, b2, dinv,
                                             out, nullptr, nullptr, N, 0);
}

// Round 10
// 321.561 us; speedup vs baseline: 1.2571x; 1.2571x over previous
//
#include <hip/hip_runtime.h>

#define NF 64        // IN_F == HID_F == 64
#define BKSH 9       // bucket = dst >> 9 (512 nodes/bucket)
#define BKN 512      // nodes per bucket
#define SB 256       // superblocks (edge partitions)

typedef unsigned short u16;
typedef __attribute__((ext_vector_type(8))) short bf16x8;
typedef __attribute__((ext_vector_type(4))) float f32x4;

__device__ __forceinline__ float bf2f(unsigned h) {
    return __uint_as_float(h << 16);
}
__device__ __forceinline__ u16 f2bf(float x) {   // round-to-nearest-even
    unsigned u = __float_as_uint(x);
    return (u16)((u + 0x7FFFu + ((u >> 16) & 1u)) >> 16);
}

// ============ CSR build: two-phase radix partition ============
// LESSONS ledger: no __threadfence last-block fusion (r6: +32us); no
// grid-shrinking fusion of streaming work (r5: +35us); no barrier-coupled
// fusion of gather phases with compute (r7: +18us); gather-table rows MUST
// be 128B-aligned -- 64B-offset base doubles random-gather FETCH (r9:
// 83->160 MB, +76us). Workspace chunks are therefore 256B-padded.

__launch_bounds__(256)
__global__ void radix_count(const int* __restrict__ dst, int* __restrict__ hist,
                            int* __restrict__ bucket_total, int E, int epb, int nbuk) {
    __shared__ int bins[BKN];
    int tid = threadIdx.x, sb = blockIdx.x;
    for (int i = tid; i < nbuk; i += 256) bins[i] = 0;
    __syncthreads();
    int base = sb * epb;
    int end = min(base + epb, E);
    for (int e = base + tid; e < end; e += 256)
        atomicAdd(&bins[dst[e] >> BKSH], 1);
    __syncthreads();
    for (int i = tid; i < nbuk; i += 256) {
        int c = bins[i];
        hist[i * SB + sb] = c;
        if (c) atomicAdd(&bucket_total[i], c);
    }
}

__global__ void hist_scan(int* __restrict__ hist, const int* __restrict__ bucket_total,
                          int nbuk) {
    __shared__ int s[256];
    int b = blockIdx.x, tid = threadIdx.x;
    // pass 1: in-block exclusive bucket base (replaces bucket_scan kernel)
    int bv = (tid < nbuk) ? bucket_total[tid] : 0;
    s[tid] = bv; __syncthreads();
    for (int off = 1; off < 256; off <<= 1) {
        int t = (tid >= off) ? s[tid - off] : 0;
        __syncthreads();
        s[tid] += t;
        __syncthreads();
    }
    int bbase = s[b] - bucket_total[b];
    __syncthreads();
    // pass 2: scan this bucket's per-superblock counts
    int v = hist[b * SB + tid];
    s[tid] = v; __syncthreads();
    for (int off = 1; off < 256; off <<= 1) {
        int t = (tid >= off) ? s[tid - off] : 0;
        __syncthreads();
        s[tid] += t;
        __syncthreads();
    }
    hist[b * SB + tid] = bbase + s[tid] - v;
}

__launch_bounds__(256)
__global__ void radix_scatter(const int* __restrict__ src, const int* __restrict__ dst,
                              const int* __restrict__ hist, int* __restrict__ tmp,
                              int E, int epb, int nbuk) {
    __shared__ int cur[BKN];
    int tid = threadIdx.x, sb = blockIdx.x;
    for (int i = tid; i < nbuk; i += 256) cur[i] = hist[i * SB + sb];
    __syncthreads();
    int base = sb * epb;
    int end = min(base + epb, E);
    for (int e = base + tid; e < end; e += 256) {
        int d = dst[e];
        int b = d >> BKSH;
        int pos = atomicAdd(&cur[b], 1);
        tmp[pos] = ((d & (BKN - 1)) << 17) | src[e];
    }
}

__launch_bounds__(256)
__global__ void radix_build(const int* __restrict__ tmp, const int* __restrict__ bucket_total,
                            int* __restrict__ csr_src, int* __restrict__ rowptr,
                            float* __restrict__ dinv, int N, int nbuk) {
    __shared__ int cnt[BKN], excl[BKN], cur[BKN];
    __shared__ int s[256];
    int b = blockIdx.x, tid = threadIdx.x;
    // in-block bucket prefix (replaces bucket_base array)
    int bv = (tid < nbuk) ? bucket_total[tid] : 0;
    s[tid] = bv; __syncthreads();
    for (int off = 1; off < 256; off <<= 1) {
        int t = (tid >= off) ? s[tid - off] : 0;
        __syncthreads();
        s[tid] += t;
        __syncthreads();
    }
    int end = s[b];
    int beg = end - bucket_total[b];
    __syncthreads();
    cnt[tid] = 0; cnt[tid + 256] = 0;
    __syncthreads();
    for (int e = beg + tid; e < end; e += 256)
        atomicAdd(&cnt[(tmp[e] >> 17) & (BKN - 1)], 1);
    __syncthreads();
    int c0 = cnt[2 * tid], c1 = cnt[2 * tid + 1];
    int v = c0 + c1;
    s[tid] = v; __syncthreads();
    for (int off = 1; off < 256; off <<= 1) {
        int t = (tid >= off) ? s[tid - off] : 0;
        __syncthreads();
        s[tid] += t;
        __syncthreads();
    }
    int base2 = s[tid] - v;
    excl[2 * tid] = base2;
    excl[2 * tid + 1] = base2 + c0;
    cur[2 * tid] = 0; cur[2 * tid + 1] = 0;
    int node0 = b << BKSH;
    int n0 = node0 + 2 * tid, n1 = n0 + 1;
    if (n0 < N) { rowptr[n0] = beg + base2;      dinv[n0] = rsqrtf(fmaxf((float)c0, 1.0f)); }
    if (n1 < N) { rowptr[n1] = beg + base2 + c0; dinv[n1] = rsqrtf(fmaxf((float)c1, 1.0f)); }
    __syncthreads();
    for (int e = beg + tid; e < end; e += 256) {
        int vv = tmp[e];
        int dlow = (vv >> 17) & (BKN - 1);
        int pos = excl[dlow] + atomicAdd(&cur[dlow], 1);
        csr_src[beg + pos] = vv & 0x1FFFF;
    }
}

// ============ prescale (+ weight transpose tail + rowptr sentinel) ============
// Ya = bf16(X*dinv), Fb = bf16(X); threads i < 192*96 also convert one W element.
__global__ void prescale(const float* __restrict__ X, const float* __restrict__ dinv,
                         u16* __restrict__ Ya, u16* __restrict__ Fb,
                         const float* __restrict__ W1, const float* __restrict__ W2,
                         u16* __restrict__ Wt1, u16* __restrict__ Wt2,
                         int* __restrict__ rowptr, int N, int E, int total4) {
    int i = blockIdx.x * blockDim.x + threadIdx.x;
    if (i == 0) rowptr[N] = E;   // sentinel (consumed first by spmm_m1, launched later)
    if (i < total4) {
        int node = i >> 4;
        float dn = dinv[node];
        float4 v = ((const float4*)X)[i];
        ushort4 ys, yu;
        ys.x = f2bf(v.x * dn); ys.y = f2bf(v.y * dn);
        ys.z = f2bf(v.z * dn); ys.w = f2bf(v.w * dn);
        yu.x = f2bf(v.x); yu.y = f2bf(v.y); yu.z = f2bf(v.z); yu.w = f2bf(v.w);
        ((ushort4*)Ya)[i] = ys;
        ((ushort4*)Fb)[i] = yu;
    }
    if (i < 192 * 64) {
        int k = i >> 6, c = i & 63;
        Wt1[(size_t)c * 192 + k] = f2bf(W1[i]);
    } else if (i < 192 * 64 + 192 * 32) {
        int j = i - 192 * 64;
        int k = j >> 5, c = j & 31;
        Wt2[(size_t)c * 192 + k] = f2bf(W2[j]);
    }
}

// ============ gather core: 8 lanes/node, x8 unroll, uint4 index loads ============
// Round-3 proven form. FETCH is at the XCD-replication compulsory floor
// (~85 MB/pass); fill path ~2.5 TB/s is the HW rate for random 128B granules.

#define ACC8(A, u) \
    A[0] += bf2f(u.x & 0xFFFFu); A[1] += bf2f(u.x >> 16); \
    A[2] += bf2f(u.y & 0xFFFFu); A[3] += bf2f(u.y >> 16); \
    A[4] += bf2f(u.z & 0xFFFFu); A[5] += bf2f(u.z >> 16); \
    A[6] += bf2f(u.w & 0xFFFFu); A[7] += bf2f(u.w >> 16);

__device__ __forceinline__ void gather8(const u16* __restrict__ Yf,
                                        const int* __restrict__ csr_src,
                                        int beg, int end, float* __restrict__ out) {
    float acc[8], acc2[8];
#pragma unroll
    for (int j = 0; j < 8; ++j) { acc[j] = 0.f; acc2[j] = 0.f; }
    int e = beg;
    int pre = min(end, (beg + 3) & ~3);            // align e to 4 for uint4 idx loads
    for (; e < pre; ++e) {
        int s = csr_src[e];
        uint4 u = *(const uint4*)(Yf + (size_t)s * NF);
        ACC8(acc, u);
    }
    for (; e + 8 <= end; e += 8) {
        uint4 sA = *(const uint4*)(csr_src + e);
        uint4 sB = *(const uint4*)(csr_src + e + 4);
        uint4 u0 = *(const uint4*)(Yf + (size_t)sA.x * NF);
        uint4 u1 = *(const uint4*)(Yf + (size_t)sA.y * NF);
        uint4 u2 = *(const uint4*)(Yf + (size_t)sA.z * NF);
        uint4 u3 = *(const uint4*)(Yf + (size_t)sA.w * NF);
        uint4 u4 = *(const uint4*)(Yf + (size_t)sB.x * NF);
        uint4 u5 = *(const uint4*)(Yf + (size_t)sB.y * NF);
        uint4 u6 = *(const uint4*)(Yf + (size_t)sB.z * NF);
        uint4 u7 = *(const uint4*)(Yf + (size_t)sB.w * NF);
        ACC8(acc, u0); ACC8(acc2, u1); ACC8(acc, u2); ACC8(acc2, u3);
        ACC8(acc, u4); ACC8(acc2, u5); ACC8(acc, u6); ACC8(acc2, u7);
    }
    if (e + 4 <= end) {
        uint4 sA = *(const uint4*)(csr_src + e);
        uint4 u0 = *(const uint4*)(Yf + (size_t)sA.x * NF);
        uint4 u1 = *(const uint4*)(Yf + (size_t)sA.y * NF);
        uint4 u2 = *(const uint4*)(Yf + (size_t)sA.z * NF);
        uint4 u3 = *(const uint4*)(Yf + (size_t)sA.w * NF);
        ACC8(acc, u0); ACC8(acc2, u1); ACC8(acc, u2); ACC8(acc2, u3);
        e += 4;
    }
    if (e + 2 <= end) {
        int2 sA = *(const int2*)(csr_src + e);
        uint4 u0 = *(const uint4*)(Yf + (size_t)sA.x * NF);
        uint4 u1 = *(const uint4*)(Yf + (size_t)sA.y * NF);
        ACC8(acc, u0); ACC8(acc2, u1);
        e += 2;
    }
    if (e < end) {
        int s = csr_src[e];
        uint4 u = *(const uint4*)(Yf + (size_t)s * NF);
        ACC8(acc, u);
    }
#pragma unroll
    for (int j = 0; j < 8; ++j) out[j] = acc[j] + acc2[j];
}

// mode 1: X1b = bf16(-acc*dinv)  (gemm operand),  Yout = bf16(-acc*dinv^2)  (next gather)
__launch_bounds__(256)
__global__ void spmm_m1(const u16* __restrict__ Y, const int* __restrict__ rowptr,
                        const int* __restrict__ csr_src, const float* __restrict__ dinv,
                        u16* __restrict__ Yout, u16* __restrict__ X1b, int n) {
    int node = (int)((blockIdx.x * blockDim.x + threadIdx.x) >> 3);
    if (node >= n) return;
    int fl = (threadIdx.x & 7) << 3;
    float acc[8];
    gather8(Y + fl, csr_src, rowptr[node], rowptr[node + 1], acc);
    float dn = dinv[node];
    float r[8];
#pragma unroll
    for (int j = 0; j < 8; ++j) r[j] = -acc[j] * dn;
    uint4 ub, uy;
    ub.x = (unsigned)f2bf(r[0]) | ((unsigned)f2bf(r[1]) << 16);
    ub.y = (unsigned)f2bf(r[2]) | ((unsigned)f2bf(r[3]) << 16);
    ub.z = (unsigned)f2bf(r[4]) | ((unsigned)f2bf(r[5]) << 16);
    ub.w = (unsigned)f2bf(r[6]) | ((unsigned)f2bf(r[7]) << 16);
    uy.x = (unsigned)f2bf(r[0] * dn) | ((unsigned)f2bf(r[1] * dn) << 16);
    uy.y = (unsigned)f2bf(r[2] * dn) | ((unsigned)f2bf(r[3] * dn) << 16);
    uy.z = (unsigned)f2bf(r[4] * dn) | ((unsigned)f2bf(r[5] * dn) << 16);
    uy.w = (unsigned)f2bf(r[6] * dn) | ((unsigned)f2bf(r[7] * dn) << 16);
    *(uint4*)(X1b + (size_t)node * NF + fl) = ub;
    *(uint4*)(Yout + (size_t)node * NF + fl) = uy;
}

// mode 2: X2b = bf16(-2*acc*dinv - Xprev),  Xprev is bf16
__launch_bounds__(256)
__global__ void spmm_m2(const u16* __restrict__ Y, const int* __restrict__ rowptr,
                        const int* __restrict__ csr_src, const float* __restrict__ dinv,
                        const u16* __restrict__ Xprev, u16* __restrict__ X2b, int n) {
    int node = (int)((blockIdx.x * blockDim.x + threadIdx.x) >> 3);
    if (node >= n) return;
    int fl = (threadIdx.x & 7) << 3;
    float acc[8];
    gather8(Y + fl, csr_src, rowptr[node], rowptr[node + 1], acc);
    float dn = dinv[node];
    uint4 up = *(const uint4*)(Xprev + (size_t)node * NF + fl);
    float xp[8];
    xp[0] = bf2f(up.x & 0xFFFFu); xp[1] = bf2f(up.x >> 16);
    xp[2] = bf2f(up.y & 0xFFFFu); xp[3] = bf2f(up.y >> 16);
    xp[4] = bf2f(up.z & 0xFFFFu); xp[5] = bf2f(up.z >> 16);
    xp[6] = bf2f(up.w & 0xFFFFu); xp[7] = bf2f(up.w >> 16);
    float r[8];
#pragma unroll
    for (int j = 0; j < 8; ++j) r[j] = -2.f * acc[j] * dn - xp[j];
    uint4 uy;
    uy.x = (unsigned)f2bf(r[0]) | ((unsigned)f2bf(r[1]) << 16);
    uy.y = (unsigned)f2bf(r[2]) | ((unsigned)f2bf(r[3]) << 16);
    uy.z = (unsigned)f2bf(r[4]) | ((unsigned)f2bf(r[5]) << 16);
    uy.w = (unsigned)f2bf(r[6]) | ((unsigned)f2bf(r[7]) << 16);
    *(uint4*)(X2b + (size_t)node * NF + fl) = uy;
}

// ============ GEMM v6 (MFMA): C[N x OUTF] = [X0b|X1b|X2b] @ W + b ============
// Wave = 16 nodes; block = 4 waves = 64 nodes. A[m=lane&15][k=q*8+j] (m120-verified),
// B symmetric via Wt[c][k] (contiguous k), D: col=lane&15, row=q*4+reg (m89-verified).
// No LDS. Layer1 (OUTF=64): writes Hb=bf16(H), Ya=bf16(H*dinv). Layer2: fp32 out.
template <int OUTF>
__launch_bounds__(256)
__global__ void gemm_mfma(const u16* __restrict__ X0b, const u16* __restrict__ X1b,
                          const u16* __restrict__ X2b, const u16* __restrict__ Wt,
                          const float* __restrict__ bias, const float* __restrict__ dinv,
                          float* __restrict__ outp, u16* __restrict__ Ya,
                          u16* __restrict__ Hb, int n, int do_relu) {
    constexpr int NT = OUTF / 16;   // 4 or 2 N-tiles
    const int wave = threadIdx.x >> 6;
    const int lane = threadIdx.x & 63;
    const int node0 = blockIdx.x * 64 + wave * 16;
    const int m = lane & 15;
    const int q = lane >> 4;
    const int arow = min(node0 + m, n - 1);   // OOB rows only corrupt unstored D rows

    union U8 { uint4 u; bf16x8 v; };

    f32x4 acc[NT];
#pragma unroll
    for (int t = 0; t < NT; ++t) acc[t] = (f32x4){0.f, 0.f, 0.f, 0.f};

    const u16* Xs[3] = {X0b, X1b, X2b};
#pragma unroll
    for (int p = 0; p < 3; ++p) {
        const u16* __restrict__ Xc = Xs[p];
#pragma unroll
        for (int h = 0; h < 2; ++h) {
            U8 a;
            a.u = *(const uint4*)(Xc + (size_t)arow * 64 + h * 32 + q * 8);
#pragma unroll
            for (int t = 0; t < NT; ++t) {
                U8 b;
                b.u = *(const uint4*)(Wt + (size_t)(t * 16 + m) * 192 + p * 64 + h * 32 + q * 8);
                acc[t] = __builtin_amdgcn_mfma_f32_16x16x32_bf16(a.v, b.v, acc[t], 0, 0, 0);
            }
        }
    }

    // epilogue: lane holds D[row=node0+q*4+r][col=t*16+m]
    float dv[4];
#pragma unroll
    for (int r = 0; r < 4; ++r) {
        int row = node0 + q * 4 + r;
        dv[r] = (OUTF == 64 && row < n) ? dinv[row] : 0.f;
    }
#pragma unroll
    for (int t = 0; t < NT; ++t) {
        int col = t * 16 + m;
        float bv = bias[col];
#pragma unroll
        for (int r = 0; r < 4; ++r) {
            int row = node0 + q * 4 + r;
            if (row < n) {
                float v = acc[t][r] + bv;
                if (do_relu) v = fmaxf(v, 0.f);
                if (OUTF == 64) {
                    Hb[(size_t)row * 64 + col] = f2bf(v);
                    Ya[(size_t)row * 64 + col] = f2bf(v * dv[r]);
                } else {
                    outp[(size_t)row * 32 + col] = v;
                }
            }
        }
    }
}

extern "C" void kernel_launch(void* const* d_in, const int* in_sizes, int n_in,
                              void* d_out, int out_size, void* d_ws, size_t ws_size,
                              hipStream_t stream) {
    const float* feat = (const float*)d_in[0];
    const int*   src  = (const int*)d_in[1];
    const int*   dst  = (const int*)d_in[2];
    const float* W1   = (const float*)d_in[3];
    const float* b1   = (const float*)d_in[4];
    const float* W2   = (const float*)d_in[5];
    const float* b2   = (const float*)d_in[6];
    float* out = (float*)d_out;

    const int N = in_sizes[0] / NF;   // 100000
    const int E = in_sizes[1];        // 1600000
    const size_t NFtot = (size_t)N * NF;
    const int nbuk = (N + BKN - 1) >> BKSH;   // 196
    const int epb = (E + SB - 1) / SB;        // 6250

    // workspace layout — every chunk padded to 256 B so the bf16 feature
    // tables (128 B/row) stay 128B-aligned (r9 lesson: 64B offset doubles
    // random-gather FETCH).
    char* p = (char*)d_ws;
    auto alloc = [&p](size_t bytes) {
        char* q = p;
        p += (bytes + 255) & ~(size_t)255;
        return q;
    };
    int* hist         = (int*)alloc((size_t)BKN * SB * 4);
    int* bucket_total = (int*)alloc((BKN + 1) * 4);
    int* rowptr       = (int*)alloc(((size_t)N + 1) * 4);
    int* csr_src      = (int*)alloc((size_t)E * 4);
    float* dinv       = (float*)alloc((size_t)N * 4);
    u16* Wt1          = (u16*)alloc(192 * 64 * 2);
    u16* Wt2          = (u16*)alloc(192 * 32 * 2);
    u16* Ya           = (u16*)alloc(NFtot * 2);   // bf16(X0*dinv) gather table
    u16* Yb           = (u16*)alloc(NFtot * 2);   // bf16(X1*dinv^2) gather table
    u16* X1b          = (u16*)alloc(NFtot * 2);   // bf16(X1) gemm operand
    u16* X2b          = (u16*)alloc(NFtot * 2);   // bf16(X2) gemm operand
    u16* Fb           = (u16*)alloc(NFtot * 2);   // bf16(feat)
    u16* Hb           = (u16*)alloc(NFtot * 2);   // bf16(H)
    int* tmp = (int*)Yb;           // alias Yb; consumed by radix_build before spmm_m1 writes Yb

    const int TB = 256;
    dim3 blk(TB);
    dim3 gW8(((size_t)N * 8 + TB - 1) / TB);    // 8 lanes per node
    dim3 gPre(((size_t)N * 16 + TB - 1) / TB);
    dim3 gGemm((N + 63) / 64);

    // ---- CSR build (radix partition; 4 kernels, no fences, no 1-block scan) ----
    hipMemsetAsync(bucket_total, 0, (size_t)(BKN + 1) * sizeof(int), stream);
    radix_count<<<dim3(SB), blk, 0, stream>>>(dst, hist, bucket_total, E, epb, nbuk);
    hist_scan<<<dim3(nbuk), blk, 0, stream>>>(hist, bucket_total, nbuk);
    radix_scatter<<<dim3(SB), blk, 0, stream>>>(src, dst, hist, tmp, E, epb, nbuk);
    radix_build<<<dim3(nbuk), blk, 0, stream>>>(tmp, bucket_total, csr_src, rowptr, dinv, N, nbuk);

    // ---- prescale + weight transpose + rowptr sentinel (one full-grid launch) ----
    prescale<<<gPre, blk, 0, stream>>>(feat, dinv, Ya, Fb, W1, W2, Wt1, Wt2,
                                       rowptr, N, E, (int)(N * 16));

    // ---- layer 1 ----
    spmm_m1<<<gW8, blk, 0, stream>>>(Ya, rowptr, csr_src, dinv, Yb, X1b, N);
    spmm_m2<<<gW8, blk, 0, stream>>>(Yb, rowptr, csr_src, dinv, Fb, X2b, N);
    gemm_mfma<64><<<gGemm, blk, 0, stream>>>(Fb, X1b, X2b, Wt1, b1, dinv,
                                             nullptr, Ya, Hb, N, 1);

    // ---- layer 2 ----
    spmm_m1<<<gW8, blk, 0, stream>>>(Ya, rowptr, csr_src, dinv, Yb, X1b, N);
    spmm_m2<<<gW8, blk, 0, stream>>>(Yb, rowptr, csr_src, dinv, Hb, X2b, N);
    gemm_mfma<32><<<gGemm, blk, 0, stream>>>(Hb, X1b, X2b, Wt2, b2, dinv,
                                             out, nullptr, nullptr, N, 0);
}